// Round 13
// baseline (200.778 us; speedup 1.0000x reference)
//
#include <hip/hip_runtime.h>
#include <hip/hip_bf16.h>

#define B_ 4
#define S_ 4096
#define E_ 1024
#define D_ 128

typedef unsigned short u16;
typedef __bf16 bf16x8 __attribute__((ext_vector_type(8)));
typedef unsigned short u16x8 __attribute__((ext_vector_type(8)));
typedef float f32x4 __attribute__((ext_vector_type(4)));

__device__ inline u16 f2bf(float f) {
    __bf16 h = (__bf16)f;
    return __builtin_bit_cast(u16, h);
}

// direct global->LDS DMA, 16B per lane, no VGPR round-trip
__device__ inline void gload16(const void* g, void* l) {
    __builtin_amdgcn_global_load_lds(
        (const __attribute__((address_space(1))) void*)g,
        (__attribute__((address_space(3))) void*)l, 16, 0, 0);
}

// ---------------------------------------------------------------------------
// Kernel 0: W [E,D] f32 -> Wt [3][D][E] bf16 (proj 0 pre-scaled by 1/sqrt(D))
// ---------------------------------------------------------------------------
__global__ __launch_bounds__(256) void wt_kernel(const float* __restrict__ Wq,
                                                 const float* __restrict__ Wk,
                                                 const float* __restrict__ Wv,
                                                 u16* __restrict__ Wt) {
    int tid = blockIdx.x * 256 + threadIdx.x;       // 0 .. 3*131072-1
    int w = tid >> 17;                               // 131072 = 2^17
    int rem = tid & 131071;
    int d = rem >> 10;
    int e = rem & 1023;
    const float* W = (w == 0) ? Wq : ((w == 1) ? Wk : Wv);
    float v = W[e * D_ + d];
    if (w == 0) v *= 0.08838834764831845f;           // 1/sqrt(128)
    Wt[tid] = f2bf(v);
}

// ---------------------------------------------------------------------------
// Kernel 1: QKV LDS-staged GEMM, M-tile 64 (r10 version — r12's M-tile 32
// grid doubling re-read W 2x through L2, costing ~11us; reverted).
// ---------------------------------------------------------------------------
__global__ __launch_bounds__(512, 4) void qkv_fused(const float* __restrict__ x,
                                                    const u16* __restrict__ Wt,
                                                    u16* __restrict__ q,
                                                    u16* __restrict__ k,
                                                    u16* __restrict__ vT) {
    const int mrow0 = blockIdx.x * 64;
    const int wv = threadIdx.x >> 6;   // 0..7
    const int l = threadIdx.x & 63;
    const int g = l >> 4;
    const int c = l & 15;
    const int wr = wv >> 2;            // 0..1 (32-row half)
    const int wc = wv & 3;             // 0..3 (96-col group)

    __shared__ __align__(16) char wlds[2][24 * 1024];   // 48 KB dbuf W-tile

    auto STAGE_W = [&](int buf, int kbase) {
#pragma unroll
        for (int ii = 0; ii < 3; ii++) {
            int ct = wv * 3 + ii;                  // 0..23
            int proj = ct >> 3;
            int dcol = (ct & 7) * 16;
            const u16* gp = Wt + ((size_t)(proj * 128 + dcol + c) * 1024 + kbase + g * 8);
            gload16(gp, wlds[buf] + ct * 1024);
        }
    };

    STAGE_W(0, 0);

    const float* xrow[2];
#pragma unroll
    for (int sub = 0; sub < 2; sub++)
        xrow[sub] = x + (size_t)(mrow0 + wr * 32 + sub * 16 + c) * E_ + g * 8;

    f32x4 acc[2][6] = {};
    __syncthreads();                 // buf0 staged (implicit vmcnt drain)

    int buf = 0;
    for (int ks = 0; ks < 32; ks++) {
        if (ks < 31) STAGE_W(buf ^ 1, (ks + 1) * 32);

        bf16x8 av[2];
#pragma unroll
        for (int sub = 0; sub < 2; sub++) {
            const float4 x0 = *(const float4*)(xrow[sub] + ks * 32);
            const float4 x1 = *(const float4*)(xrow[sub] + ks * 32 + 4);
            union { bf16x8 v; __bf16 e[8]; } a;
            a.e[0] = (__bf16)x0.x; a.e[1] = (__bf16)x0.y;
            a.e[2] = (__bf16)x0.z; a.e[3] = (__bf16)x0.w;
            a.e[4] = (__bf16)x1.x; a.e[5] = (__bf16)x1.y;
            a.e[6] = (__bf16)x1.z; a.e[7] = (__bf16)x1.w;
            av[sub] = a.v;
        }

#pragma unroll
        for (int ct = 0; ct < 6; ct++) {
            u16x8 braw = *(const u16x8*)(wlds[buf] + (wc * 6 + ct) * 1024 + l * 16);
            bf16x8 bw = __builtin_bit_cast(bf16x8, braw);
#pragma unroll
            for (int sub = 0; sub < 2; sub++)
                acc[sub][ct] = __builtin_amdgcn_mfma_f32_16x16x32_bf16(av[sub], bw, acc[sub][ct], 0, 0, 0);
        }

        __syncthreads();             // reads done + next-buf staging drained
        buf ^= 1;
    }

#pragma unroll
    for (int sub = 0; sub < 2; sub++) {
#pragma unroll
        for (int ct = 0; ct < 6; ct++) {
            int gc = (wc * 6 + ct) * 16;
            int proj = gc >> 7;
            int dcol = gc & 127;
            if (proj < 2) {
                u16* dst = proj ? k : q;
#pragma unroll
                for (int j = 0; j < 4; j++) {
                    int row = mrow0 + wr * 32 + sub * 16 + g * 4 + j;
                    dst[(size_t)row * D_ + dcol + c] = f2bf(acc[sub][ct][j]);
                }
            } else {
                int srow = mrow0 + wr * 32 + sub * 16 + g * 4;
                int b = srow >> 12;
                int s = srow & 4095;
                ushort4 pk;
                pk.x = f2bf(acc[sub][ct][0]);
                pk.y = f2bf(acc[sub][ct][1]);
                pk.z = f2bf(acc[sub][ct][2]);
                pk.w = f2bf(acc[sub][ct][3]);
                *(ushort4*)(vT + ((size_t)(b * D_ + dcol + c)) * S_ + s) = pk;
            }
        }
    }
}

// ---------------------------------------------------------------------------
// Kernel 2: flash attention — exact r10 schedule (KVBLK=64, even/odd 2-way
// split, dbuf, ONE barrier per round, shfl_xor softmax) + ONLY the two
// positively-evidenced grafts:
//  - fragment-order K/V staging [frag][lane][16B]: ds_reads are base+l*16
//    (linear, conflict-free: r12 measured 4.3M -> 131K conflict cycles);
//    the per-lane GLOBAL source address realizes the layout.
//  - defer-max (T13, THR=8): skip alpha-rescale unless a tile max grows.
// Removed from r12 (suspected regressors, unverified/negative evidence):
// DPP reduce (8 serial 4-hop chains on VALU critical path), setprio
// (8-wave lockstep = m190 GEMM regime, measured -14 there).
// ---------------------------------------------------------------------------
__global__ __launch_bounds__(512) void attn_kernel(const u16* __restrict__ q,
                                                   const u16* __restrict__ k,
                                                   const u16* __restrict__ vT,
                                                   float* __restrict__ out) {
    // bijective XCD-chunk swizzle (nwg=256, 8 XCDs, chunk=32)
    int bid = blockIdx.x;
    int sw = (bid & 7) * 32 + (bid >> 3);
    const int b = sw >> 6;          // batch 0..3 (2 XCDs per batch)
    const int qt = sw & 63;         // q-tile 0..63 (64 rows)
    const int wv = threadIdx.x >> 6;    // 0..7
    const int grp = wv >> 2;            // 0 = even tiles, 1 = odd tiles
    const int wq = wv & 3;              // q-subtile within block
    const int l = threadIdx.x & 63;
    const int g = l >> 4;
    const int c = l & 15;
    const int qrow0 = qt * 64 + wq * 16;   // within batch

    __shared__ __align__(16) char kv_lds[4 * 32768];   // 4 bufs (K 16K | V 16K)
    __shared__ __align__(16) u16 plds[8][1024];        // per-wave 2KB P buffer
    __shared__ float cmB[64], clB[64];
    u16* pw = &plds[wv][0];

    const char* kbb = (const char*)(k + (size_t)b * S_ * D_);
    const char* vbb = (const char*)(vT + (size_t)b * D_ * S_);

    // Q fragments, hoisted (scaled already, via Wq)
    bf16x8 aq[4];
    const u16* qp = q + ((size_t)(b * S_ + qrow0 + c)) * D_ + g * 8;
#pragma unroll
    for (int ks = 0; ks < 4; ks++) aq[ks] = *(const bf16x8*)(qp + ks * 32);

    f32x4 o[8] = {};
    float m[4], ll[4];
#pragma unroll
    for (int j = 0; j < 4; j++) { m[j] = -1e30f; ll[j] = 0.0f; }

    // stage one 64-kv tile in FRAGMENT ORDER; 8 instrs per wave (4 waves/grp).
    // K frag (tt,ks): lane l -> K[kvbase+tt*16+(l&15)][ks*32+(l>>4)*8 ..+8]
    // V frag (st,ct): lane l -> vT[ct*16+(l&15)][kvbase+st*32+(l>>4)*8 ..+8]
    auto STAGE = [&](int buf, int kvbase) {
        char* base = kv_lds + buf * 32768;
#pragma unroll
        for (int ii = 0; ii < 4; ii++) {       // K frags idx = tt*4+ks
            int idx = wq * 4 + ii;             // 0..15
            int tt = idx >> 2, ks = idx & 3;
            const char* gp = kbb + (size_t)(kvbase + tt * 16 + c) * 256 + ks * 64 + g * 16;
            gload16(gp, base + idx * 1024);
        }
#pragma unroll
        for (int ii = 0; ii < 4; ii++) {       // V frags idx2 = st*8+ct
            int idx2 = wq * 4 + ii;            // 0..15 over grp's 4 waves
            int st = idx2 >> 3, ct = idx2 & 7;
            const char* gp = vbb + (size_t)(ct * 16 + c) * 8192 + (size_t)kvbase * 2 + st * 64 + g * 16;
            gload16(gp, base + 16384 + idx2 * 1024);
        }
    };

    STAGE(grp, grp * 64);
    __syncthreads();                 // drains vmcnt: bufs 0,1 ready

    for (int t = 0; t < 32; t++) {
        const int mytile = 2 * t + grp;
        if (t < 31) STAGE((mytile + 2) & 3, (mytile + 2) * 64);

        const char* kbuf = kv_lds + (mytile & 3) * 32768;
        const char* vbuf = kbuf + 16384;

        // ---- S = Q K^T : 4 tiles of 16 kv-cols, K-dim 128 ----
        f32x4 s[4] = {};
#pragma unroll
        for (int tt = 0; tt < 4; tt++) {
#pragma unroll
            for (int ks = 0; ks < 4; ks++) {
                u16x8 kr = *(const u16x8*)(kbuf + (tt * 4 + ks) * 1024 + l * 16);
                bf16x8 bk = __builtin_bit_cast(bf16x8, kr);
                s[tt] = __builtin_amdgcn_mfma_f32_16x16x32_bf16(aq[ks], bk, s[tt], 0, 0, 0);
            }
        }

        // ---- online softmax: shfl_xor reduce + defer-max (THR=8) ----
        float tmj[4];
        bool need = false;
#pragma unroll
        for (int j = 0; j < 4; j++) {
            float tm = fmaxf(fmaxf(s[0][j], s[1][j]), fmaxf(s[2][j], s[3][j]));
            tm = fmaxf(tm, __shfl_xor(tm, 1));
            tm = fmaxf(tm, __shfl_xor(tm, 2));
            tm = fmaxf(tm, __shfl_xor(tm, 4));
            tm = fmaxf(tm, __shfl_xor(tm, 8));
            tmj[j] = tm;
            need = need || (tm > m[j] + 8.0f);
        }
        if (__any(need)) {
#pragma unroll
            for (int j = 0; j < 4; j++) {
                float mn = fmaxf(m[j], tmj[j]);
                float alpha = exp2f((m[j] - mn) * 1.44269504f);
                ll[j] *= alpha;
#pragma unroll
                for (int ct = 0; ct < 8; ct++) o[ct][j] *= alpha;
                m[j] = mn;
            }
        }
        float pv[4][4];
#pragma unroll
        for (int j = 0; j < 4; j++) {
            float rs = 0.f;
#pragma unroll
            for (int tt = 0; tt < 4; tt++) {
                float p = exp2f((s[tt][j] - m[j]) * 1.44269504f);
                pv[tt][j] = p;
                rs += p;
            }
            rs += __shfl_xor(rs, 1);
            rs += __shfl_xor(rs, 2);
            rs += __shfl_xor(rs, 4);
            rs += __shfl_xor(rs, 8);
            ll[j] += rs;
        }

        // ---- P -> LDS (wave-private), XOR-swizzled ----
#pragma unroll
        for (int tt = 0; tt < 4; tt++) {
#pragma unroll
            for (int j = 0; j < 4; j++) {
                int r = g * 4 + j;
                int cf = tt * 16 + c;
                int slot = (cf >> 3) ^ ((r & 7) ^ ((r & 8) >> 2));
                pw[r * 64 + slot * 8 + (cf & 7)] = f2bf(pv[tt][j]);
            }
        }

        // ---- PV: O += P[16,64] * V[64,128] ----
#pragma unroll
        for (int st = 0; st < 2; st++) {
            int rho = c;
            int sigma = g + st * 4;
            int slot = sigma ^ ((rho & 7) ^ ((rho & 8) >> 2));
            u16x8 praw = *(const u16x8*)(pw + rho * 64 + slot * 8);
            bf16x8 pa = __builtin_bit_cast(bf16x8, praw);
#pragma unroll
            for (int ct = 0; ct < 8; ct++) {
                u16x8 vr = *(const u16x8*)(vbuf + (st * 8 + ct) * 1024 + l * 16);
                bf16x8 bv = __builtin_bit_cast(bf16x8, vr);
                o[ct] = __builtin_amdgcn_mfma_f32_16x16x32_bf16(pa, bv, o[ct], 0, 0, 0);
            }
        }

        __syncthreads();    // drain staging vmcnt + round barrier
    }

    // ---- 2-way merge: grp 1 -> LDS, grp 0 merges and stores ----
    float* co = (float*)kv_lds;     // 32KB, staging complete
    if (grp == 1) {
#pragma unroll
        for (int ct = 0; ct < 8; ct++) {
#pragma unroll
            for (int j = 0; j < 4; j++)
                co[(size_t)(wq * 16 + g * 4 + j) * 128 + ct * 16 + c] = o[ct][j];
        }
        if (c == 0) {
#pragma unroll
            for (int j = 0; j < 4; j++) {
                cmB[wq * 16 + g * 4 + j] = m[j];
                clB[wq * 16 + g * 4 + j] = ll[j];
            }
        }
    }
    __syncthreads();
    if (grp == 0) {
#pragma unroll
        for (int j = 0; j < 4; j++) {
            int r = wq * 16 + g * 4 + j;
            float mB = cmB[r], lB = clB[r];
            float M = fmaxf(m[j], mB);
            float eA = exp2f((m[j] - M) * 1.44269504f);
            float eB = exp2f((mB - M) * 1.44269504f);
            float rL = 1.0f / (ll[j] * eA + lB * eB);
            float* op = out + ((size_t)(b * S_ + qt * 64 + r)) * D_;
#pragma unroll
            for (int ct = 0; ct < 8; ct++) {
                op[ct * 16 + c] = (o[ct][j] * eA + co[(size_t)r * 128 + ct * 16 + c] * eB) * rL;
            }
        }
    }
}

extern "C" void kernel_launch(void* const* d_in, const int* in_sizes, int n_in,
                              void* d_out, int out_size, void* d_ws, size_t ws_size,
                              hipStream_t stream) {
    const float* x  = (const float*)d_in[0];
    const float* Wq = (const float*)d_in[1];
    const float* Wk = (const float*)d_in[2];
    const float* Wv = (const float*)d_in[3];
    float* out = (float*)d_out;   // reference output dtype is float32

    // workspace layout (bytes): q 4MB | k 4MB | vT 4MB | Wt 768KB
    u16* q  = (u16*)d_ws;
    u16* k  = q  + (size_t)B_ * S_ * D_;
    u16* vT = k  + (size_t)B_ * S_ * D_;
    u16* Wt = vT + (size_t)B_ * S_ * D_;

    wt_kernel<<<(3 * D_ * E_) / 256, 256, 0, stream>>>(Wq, Wk, Wv, Wt);
    qkv_fused<<<(B_ * S_) / 64, 512, 0, stream>>>(x, Wt, q, k, vT);
    attn_kernel<<<(B_ * S_) / 64, 512, 0, stream>>>(q, k, vT, out);
}

// Round 14
// 165.962 us; speedup vs baseline: 1.2098x; 1.2098x over previous
//
#include <hip/hip_runtime.h>
#include <hip/hip_bf16.h>

#define B_ 4
#define S_ 4096
#define E_ 1024
#define D_ 128

typedef unsigned short u16;
typedef __bf16 bf16x8 __attribute__((ext_vector_type(8)));
typedef unsigned short u16x8 __attribute__((ext_vector_type(8)));
typedef float f32x4 __attribute__((ext_vector_type(4)));

__device__ inline u16 f2bf(float f) {
    __bf16 h = (__bf16)f;
    return __builtin_bit_cast(u16, h);
}

// direct global->LDS DMA, 16B per lane, no VGPR round-trip
__device__ inline void gload16(const void* g, void* l) {
    __builtin_amdgcn_global_load_lds(
        (const __attribute__((address_space(1))) void*)g,
        (__attribute__((address_space(3))) void*)l, 16, 0, 0);
}

// VALU-pipe (DPP) butterfly reductions over 16-lane rows: xor1, xor2,
// xor7 (row_half_mirror), xor15 (row_mirror) — valid reduction network.
// (numerically verified: r12 passed with identical absmax)
__device__ inline float dpp_max16(float x) {
    int v = __builtin_bit_cast(int, x);
    x = fmaxf(x, __builtin_bit_cast(float, __builtin_amdgcn_update_dpp(0, v, 0xB1, 0xF, 0xF, true)));
    v = __builtin_bit_cast(int, x);
    x = fmaxf(x, __builtin_bit_cast(float, __builtin_amdgcn_update_dpp(0, v, 0x4E, 0xF, 0xF, true)));
    v = __builtin_bit_cast(int, x);
    x = fmaxf(x, __builtin_bit_cast(float, __builtin_amdgcn_update_dpp(0, v, 0x141, 0xF, 0xF, true)));
    v = __builtin_bit_cast(int, x);
    x = fmaxf(x, __builtin_bit_cast(float, __builtin_amdgcn_update_dpp(0, v, 0x140, 0xF, 0xF, true)));
    return x;
}
__device__ inline float dpp_add16(float x) {
    int v = __builtin_bit_cast(int, x);
    x += __builtin_bit_cast(float, __builtin_amdgcn_update_dpp(0, v, 0xB1, 0xF, 0xF, true));
    v = __builtin_bit_cast(int, x);
    x += __builtin_bit_cast(float, __builtin_amdgcn_update_dpp(0, v, 0x4E, 0xF, 0xF, true));
    v = __builtin_bit_cast(int, x);
    x += __builtin_bit_cast(float, __builtin_amdgcn_update_dpp(0, v, 0x141, 0xF, 0xF, true));
    v = __builtin_bit_cast(int, x);
    x += __builtin_bit_cast(float, __builtin_amdgcn_update_dpp(0, v, 0x140, 0xF, 0xF, true));
    return x;
}

// ---------------------------------------------------------------------------
// Kernel 0: W [E,D] f32 -> Wt [3][D][E] bf16 (proj 0 pre-scaled by 1/sqrt(D))
// ---------------------------------------------------------------------------
__global__ __launch_bounds__(256) void wt_kernel(const float* __restrict__ Wq,
                                                 const float* __restrict__ Wk,
                                                 const float* __restrict__ Wv,
                                                 u16* __restrict__ Wt) {
    int tid = blockIdx.x * 256 + threadIdx.x;       // 0 .. 3*131072-1
    int w = tid >> 17;                               // 131072 = 2^17
    int rem = tid & 131071;
    int d = rem >> 10;
    int e = rem & 1023;
    const float* W = (w == 0) ? Wq : ((w == 1) ? Wk : Wv);
    float v = W[e * D_ + d];
    if (w == 0) v *= 0.08838834764831845f;           // 1/sqrt(128)
    Wt[tid] = f2bf(v);
}

// ---------------------------------------------------------------------------
// Kernel 1: QKV LDS-staged GEMM, M-tile 64 (r10 version, ~60us).
// ---------------------------------------------------------------------------
__global__ __launch_bounds__(512, 4) void qkv_fused(const float* __restrict__ x,
                                                    const u16* __restrict__ Wt,
                                                    u16* __restrict__ q,
                                                    u16* __restrict__ k,
                                                    u16* __restrict__ vT) {
    const int mrow0 = blockIdx.x * 64;
    const int wv = threadIdx.x >> 6;   // 0..7
    const int l = threadIdx.x & 63;
    const int g = l >> 4;
    const int c = l & 15;
    const int wr = wv >> 2;            // 0..1 (32-row half)
    const int wc = wv & 3;             // 0..3 (96-col group)

    __shared__ __align__(16) char wlds[2][24 * 1024];   // 48 KB dbuf W-tile

    auto STAGE_W = [&](int buf, int kbase) {
#pragma unroll
        for (int ii = 0; ii < 3; ii++) {
            int ct = wv * 3 + ii;                  // 0..23
            int proj = ct >> 3;
            int dcol = (ct & 7) * 16;
            const u16* gp = Wt + ((size_t)(proj * 128 + dcol + c) * 1024 + kbase + g * 8);
            gload16(gp, wlds[buf] + ct * 1024);
        }
    };

    STAGE_W(0, 0);

    const float* xrow[2];
#pragma unroll
    for (int sub = 0; sub < 2; sub++)
        xrow[sub] = x + (size_t)(mrow0 + wr * 32 + sub * 16 + c) * E_ + g * 8;

    f32x4 acc[2][6] = {};
    __syncthreads();                 // buf0 staged (implicit vmcnt drain)

    int buf = 0;
    for (int ks = 0; ks < 32; ks++) {
        if (ks < 31) STAGE_W(buf ^ 1, (ks + 1) * 32);

        bf16x8 av[2];
#pragma unroll
        for (int sub = 0; sub < 2; sub++) {
            const float4 x0 = *(const float4*)(xrow[sub] + ks * 32);
            const float4 x1 = *(const float4*)(xrow[sub] + ks * 32 + 4);
            union { bf16x8 v; __bf16 e[8]; } a;
            a.e[0] = (__bf16)x0.x; a.e[1] = (__bf16)x0.y;
            a.e[2] = (__bf16)x0.z; a.e[3] = (__bf16)x0.w;
            a.e[4] = (__bf16)x1.x; a.e[5] = (__bf16)x1.y;
            a.e[6] = (__bf16)x1.z; a.e[7] = (__bf16)x1.w;
            av[sub] = a.v;
        }

#pragma unroll
        for (int ct = 0; ct < 6; ct++) {
            u16x8 braw = *(const u16x8*)(wlds[buf] + (wc * 6 + ct) * 1024 + l * 16);
            bf16x8 bw = __builtin_bit_cast(bf16x8, braw);
#pragma unroll
            for (int sub = 0; sub < 2; sub++)
                acc[sub][ct] = __builtin_amdgcn_mfma_f32_16x16x32_bf16(av[sub], bw, acc[sub][ct], 0, 0, 0);
        }

        __syncthreads();             // reads done + next-buf staging drained
        buf ^= 1;
    }

#pragma unroll
    for (int sub = 0; sub < 2; sub++) {
#pragma unroll
        for (int ct = 0; ct < 6; ct++) {
            int gc = (wc * 6 + ct) * 16;
            int proj = gc >> 7;
            int dcol = gc & 127;
            if (proj < 2) {
                u16* dst = proj ? k : q;
#pragma unroll
                for (int j = 0; j < 4; j++) {
                    int row = mrow0 + wr * 32 + sub * 16 + g * 4 + j;
                    dst[(size_t)row * D_ + dcol + c] = f2bf(acc[sub][ct][j]);
                }
            } else {
                int srow = mrow0 + wr * 32 + sub * 16 + g * 4;
                int b = srow >> 12;
                int s = srow & 4095;
                ushort4 pk;
                pk.x = f2bf(acc[sub][ct][0]);
                pk.y = f2bf(acc[sub][ct][1]);
                pk.z = f2bf(acc[sub][ct][2]);
                pk.w = f2bf(acc[sub][ct][3]);
                *(ushort4*)(vT + ((size_t)(b * D_ + dcol + c)) * S_ + s) = pk;
            }
        }
    }
}

// ---------------------------------------------------------------------------
// Kernel 2: flash attention — r10 schedule AND r10 staging (XOR-swizzled,
// 256B-contiguous global source: the r12/r13 fragment-order staging read
// 16x64B scattered segments per gload_lds -> 4x L2 transactions, and the
// per-round barrier vmcnt(0) drain put that directly on the critical path;
// +31us measured) + the r12/r13-evidenced winners:
//  - DPP softmax reduce + setprio around MFMA clusters (r13->r12: -12us)
//  - defer-max (T13, THR=8)
// ---------------------------------------------------------------------------
__global__ __launch_bounds__(512) void attn_kernel(const u16* __restrict__ q,
                                                   const u16* __restrict__ k,
                                                   const u16* __restrict__ vT,
                                                   float* __restrict__ out) {
    // bijective XCD-chunk swizzle (nwg=256, 8 XCDs, chunk=32)
    int bid = blockIdx.x;
    int sw = (bid & 7) * 32 + (bid >> 3);
    const int b = sw >> 6;          // batch 0..3 (2 XCDs per batch)
    const int qt = sw & 63;         // q-tile 0..63 (64 rows)
    const int wv = threadIdx.x >> 6;    // 0..7
    const int grp = wv >> 2;            // 0 = even tiles, 1 = odd tiles
    const int wq = wv & 3;              // q-subtile within block
    const int l = threadIdx.x & 63;
    const int g = l >> 4;
    const int c = l & 15;
    const int qrow0 = qt * 64 + wq * 16;   // within batch

    __shared__ __align__(16) char kv_lds[4 * 32768];   // 4 bufs (K 16K | V 16K)
    __shared__ __align__(16) u16 plds[8][1024];        // per-wave 2KB P buffer
    __shared__ float cmB[64], clB[64];
    u16* pw = &plds[wv][0];

    const char* kbb = (const char*)(k + (size_t)b * S_ * D_);
    const char* vbb = (const char*)(vT + (size_t)b * D_ * S_);

    // Q fragments, hoisted (scaled already, via Wq)
    bf16x8 aq[4];
    const u16* qp = q + ((size_t)(b * S_ + qrow0 + c)) * D_ + g * 8;
#pragma unroll
    for (int ks = 0; ks < 4; ks++) aq[ks] = *(const bf16x8*)(qp + ks * 32);

    f32x4 o[8] = {};
    float m[4], ll[4];
#pragma unroll
    for (int j = 0; j < 4; j++) { m[j] = -1e30f; ll[j] = 0.0f; }

    // r10 staging: row-major chunks, XOR-swizzled LDS layout realized by
    // inverse-swizzling the 256B-contiguous global SOURCE (linear dest).
    auto STAGE = [&](int buf, int kvbase) {
#pragma unroll
        for (int ii = 0; ii < 4; ii++) {           // K: [64][256B] rows
            int i = wq * 4 + ii;                   // instr 0..15, 1KB each
            int row = i * 4 + (l >> 4);
            int colb = (l & 15) * 16;
            const char* gp = kbb + (size_t)kvbase * 256 + (size_t)row * 256
                           + (colb ^ ((row & 7) << 4));
            gload16(gp, kv_lds + buf * 32768 + i * 1024);
        }
#pragma unroll
        for (int ii = 0; ii < 4; ii++) {           // V: [128][128B] rows
            int i = wq * 4 + ii;
            int row = i * 8 + (l >> 3);
            int colb = (l & 7) * 16;
            const char* gp = vbb + (size_t)row * 8192 + (size_t)kvbase * 2
                           + (colb ^ ((row & 7) << 4));
            gload16(gp, kv_lds + buf * 32768 + 16384 + i * 1024);
        }
    };

    STAGE(grp, grp * 64);
    __syncthreads();                 // drains vmcnt: bufs 0,1 ready
    const int swz = (c & 7) << 4;

    for (int t = 0; t < 32; t++) {
        const int mytile = 2 * t + grp;
        if (t < 31) STAGE((mytile + 2) & 3, (mytile + 2) * 64);

        const char* kbuf = kv_lds + (mytile & 3) * 32768;
        const char* vbuf = kbuf + 16384;

        // ---- S = Q K^T : 4 tiles of 16 kv-cols, K-dim 128 ----
        f32x4 s[4] = {};
        __builtin_amdgcn_s_setprio(1);
#pragma unroll
        for (int tt = 0; tt < 4; tt++) {
            int rb = (tt * 16 + c) * 256;
#pragma unroll
            for (int ks = 0; ks < 4; ks++) {
                u16x8 kr = *(const u16x8*)(kbuf + rb + ((ks * 64 + g * 16) ^ swz));
                bf16x8 bk = __builtin_bit_cast(bf16x8, kr);
                s[tt] = __builtin_amdgcn_mfma_f32_16x16x32_bf16(aq[ks], bk, s[tt], 0, 0, 0);
            }
        }
        __builtin_amdgcn_s_setprio(0);

        // ---- online softmax: DPP reduce + defer-max (THR=8) ----
        float tmj[4];
        bool need = false;
#pragma unroll
        for (int j = 0; j < 4; j++) {
            float tm = fmaxf(fmaxf(s[0][j], s[1][j]), fmaxf(s[2][j], s[3][j]));
            tm = dpp_max16(tm);
            tmj[j] = tm;
            need = need || (tm > m[j] + 8.0f);
        }
        if (__any(need)) {
#pragma unroll
            for (int j = 0; j < 4; j++) {
                float mn = fmaxf(m[j], tmj[j]);
                float alpha = exp2f((m[j] - mn) * 1.44269504f);
                ll[j] *= alpha;
#pragma unroll
                for (int ct = 0; ct < 8; ct++) o[ct][j] *= alpha;
                m[j] = mn;
            }
        }
        float pv[4][4];
#pragma unroll
        for (int j = 0; j < 4; j++) {
            float rs = 0.f;
#pragma unroll
            for (int tt = 0; tt < 4; tt++) {
                float p = exp2f((s[tt][j] - m[j]) * 1.44269504f);
                pv[tt][j] = p;
                rs += p;
            }
            ll[j] += dpp_add16(rs);
        }

        // ---- P -> LDS (wave-private), XOR-swizzled ----
#pragma unroll
        for (int tt = 0; tt < 4; tt++) {
#pragma unroll
            for (int j = 0; j < 4; j++) {
                int r = g * 4 + j;
                int cf = tt * 16 + c;
                int slot = (cf >> 3) ^ ((r & 7) ^ ((r & 8) >> 2));
                pw[r * 64 + slot * 8 + (cf & 7)] = f2bf(pv[tt][j]);
            }
        }

        // ---- PV: O += P[16,64] * V[64,128] ----
        __builtin_amdgcn_s_setprio(1);
#pragma unroll
        for (int st = 0; st < 2; st++) {
            int rho = c;
            int sigma = g + st * 4;
            int slot = sigma ^ ((rho & 7) ^ ((rho & 8) >> 2));
            u16x8 praw = *(const u16x8*)(pw + rho * 64 + slot * 8);
            bf16x8 pa = __builtin_bit_cast(bf16x8, praw);
#pragma unroll
            for (int ct = 0; ct < 8; ct++) {
                int rb = (ct * 16 + c) * 128;
                u16x8 vr = *(const u16x8*)(vbuf + rb + ((st * 64 + g * 16) ^ swz));
                bf16x8 bv = __builtin_bit_cast(bf16x8, vr);
                o[ct] = __builtin_amdgcn_mfma_f32_16x16x32_bf16(pa, bv, o[ct], 0, 0, 0);
            }
        }
        __builtin_amdgcn_s_setprio(0);

        __syncthreads();    // drain staging vmcnt + round barrier
    }

    // ---- 2-way merge: grp 1 -> LDS, grp 0 merges and stores ----
    float* co = (float*)kv_lds;     // 32KB, staging complete
    if (grp == 1) {
#pragma unroll
        for (int ct = 0; ct < 8; ct++) {
#pragma unroll
            for (int j = 0; j < 4; j++)
                co[(size_t)(wq * 16 + g * 4 + j) * 128 + ct * 16 + c] = o[ct][j];
        }
        if (c == 0) {
#pragma unroll
            for (int j = 0; j < 4; j++) {
                cmB[wq * 16 + g * 4 + j] = m[j];
                clB[wq * 16 + g * 4 + j] = ll[j];
            }
        }
    }
    __syncthreads();
    if (grp == 0) {
#pragma unroll
        for (int j = 0; j < 4; j++) {
            int r = wq * 16 + g * 4 + j;
            float mB = cmB[r], lB = clB[r];
            float M = fmaxf(m[j], mB);
            float eA = exp2f((m[j] - M) * 1.44269504f);
            float eB = exp2f((mB - M) * 1.44269504f);
            float rL = 1.0f / (ll[j] * eA + lB * eB);
            float* op = out + ((size_t)(b * S_ + qt * 64 + r)) * D_;
#pragma unroll
            for (int ct = 0; ct < 8; ct++) {
                op[ct * 16 + c] = (o[ct][j] * eA + co[(size_t)r * 128 + ct * 16 + c] * eB) * rL;
            }
        }
    }
}

extern "C" void kernel_launch(void* const* d_in, const int* in_sizes, int n_in,
                              void* d_out, int out_size, void* d_ws, size_t ws_size,
                              hipStream_t stream) {
    const float* x  = (const float*)d_in[0];
    const float* Wq = (const float*)d_in[1];
    const float* Wk = (const float*)d_in[2];
    const float* Wv = (const float*)d_in[3];
    float* out = (float*)d_out;   // reference output dtype is float32

    // workspace layout (bytes): q 4MB | k 4MB | vT 4MB | Wt 768KB
    u16* q  = (u16*)d_ws;
    u16* k  = q  + (size_t)B_ * S_ * D_;
    u16* vT = k  + (size_t)B_ * S_ * D_;
    u16* Wt = vT + (size_t)B_ * S_ * D_;

    wt_kernel<<<(3 * D_ * E_) / 256, 256, 0, stream>>>(Wq, Wk, Wv, Wt);
    qkv_fused<<<(B_ * S_) / 64, 512, 0, stream>>>(x, Wt, q, k, vT);
    attn_kernel<<<(B_ * S_) / 64, 512, 0, stream>>>(q, k, vT, out);
}

// Round 15
// 160.987 us; speedup vs baseline: 1.2472x; 1.0309x over previous
//
#include <hip/hip_runtime.h>
#include <hip/hip_bf16.h>

#define B_ 4
#define S_ 4096
#define E_ 1024
#define D_ 128

typedef unsigned short u16;
typedef __bf16 bf16x8 __attribute__((ext_vector_type(8)));
typedef unsigned short u16x8 __attribute__((ext_vector_type(8)));
typedef float f32x4 __attribute__((ext_vector_type(4)));

__device__ inline u16 f2bf(float f) {
    __bf16 h = (__bf16)f;
    return __builtin_bit_cast(u16, h);
}

// direct global->LDS DMA, 16B per lane, no VGPR round-trip
__device__ inline void gload16(const void* g, void* l) {
    __builtin_amdgcn_global_load_lds(
        (const __attribute__((address_space(1))) void*)g,
        (__attribute__((address_space(3))) void*)l, 16, 0, 0);
}

// VALU-pipe (DPP) butterfly reductions over 16-lane rows.
__device__ inline float dpp_max16(float x) {
    int v = __builtin_bit_cast(int, x);
    x = fmaxf(x, __builtin_bit_cast(float, __builtin_amdgcn_update_dpp(0, v, 0xB1, 0xF, 0xF, true)));
    v = __builtin_bit_cast(int, x);
    x = fmaxf(x, __builtin_bit_cast(float, __builtin_amdgcn_update_dpp(0, v, 0x4E, 0xF, 0xF, true)));
    v = __builtin_bit_cast(int, x);
    x = fmaxf(x, __builtin_bit_cast(float, __builtin_amdgcn_update_dpp(0, v, 0x141, 0xF, 0xF, true)));
    v = __builtin_bit_cast(int, x);
    x = fmaxf(x, __builtin_bit_cast(float, __builtin_amdgcn_update_dpp(0, v, 0x140, 0xF, 0xF, true)));
    return x;
}
__device__ inline float dpp_add16(float x) {
    int v = __builtin_bit_cast(int, x);
    x += __builtin_bit_cast(float, __builtin_amdgcn_update_dpp(0, v, 0xB1, 0xF, 0xF, true));
    v = __builtin_bit_cast(int, x);
    x += __builtin_bit_cast(float, __builtin_amdgcn_update_dpp(0, v, 0x4E, 0xF, 0xF, true));
    v = __builtin_bit_cast(int, x);
    x += __builtin_bit_cast(float, __builtin_amdgcn_update_dpp(0, v, 0x141, 0xF, 0xF, true));
    v = __builtin_bit_cast(int, x);
    x += __builtin_bit_cast(float, __builtin_amdgcn_update_dpp(0, v, 0x140, 0xF, 0xF, true));
    return x;
}

// ---------------------------------------------------------------------------
// Kernel 0: W [E,D] f32 -> Wt [3][D][E] bf16 (proj 0 pre-scaled by 1/sqrt(D))
// ---------------------------------------------------------------------------
__global__ __launch_bounds__(256) void wt_kernel(const float* __restrict__ Wq,
                                                 const float* __restrict__ Wk,
                                                 const float* __restrict__ Wv,
                                                 u16* __restrict__ Wt) {
    int tid = blockIdx.x * 256 + threadIdx.x;       // 0 .. 3*131072-1
    int w = tid >> 17;                               // 131072 = 2^17
    int rem = tid & 131071;
    int d = rem >> 10;
    int e = rem & 1023;
    const float* W = (w == 0) ? Wq : ((w == 1) ? Wk : Wv);
    float v = W[e * D_ + d];
    if (w == 0) v *= 0.08838834764831845f;           // 1/sqrt(128)
    Wt[tid] = f2bf(v);
}

// ---------------------------------------------------------------------------
// Kernel 1: QKV LDS-staged GEMM, M-tile 64 + SOFTWARE-PIPELINED x loads.
// r14 diagnosis: x loads were issued at step start and consumed immediately;
// the inter-step __syncthreads blocks compiler hoisting, so all 32 steps
// serially ate ~500-900cyc of x-load latency (1 block/CU, nothing covers).
// Now x for step ks+1 is loaded into registers BEFORE step ks's MFMA
// cluster; the end-of-step barrier completes (not stalls at use) them.
// ---------------------------------------------------------------------------
__global__ __launch_bounds__(512, 4) void qkv_fused(const float* __restrict__ x,
                                                    const u16* __restrict__ Wt,
                                                    u16* __restrict__ q,
                                                    u16* __restrict__ k,
                                                    u16* __restrict__ vT) {
    const int mrow0 = blockIdx.x * 64;
    const int wv = threadIdx.x >> 6;   // 0..7
    const int l = threadIdx.x & 63;
    const int g = l >> 4;
    const int c = l & 15;
    const int wr = wv >> 2;            // 0..1 (32-row half)
    const int wc = wv & 3;             // 0..3 (96-col group)

    __shared__ __align__(16) char wlds[2][24 * 1024];   // 48 KB dbuf W-tile

    auto STAGE_W = [&](int buf, int kbase) {
#pragma unroll
        for (int ii = 0; ii < 3; ii++) {
            int ct = wv * 3 + ii;                  // 0..23
            int proj = ct >> 3;
            int dcol = (ct & 7) * 16;
            const u16* gp = Wt + ((size_t)(proj * 128 + dcol + c) * 1024 + kbase + g * 8);
            gload16(gp, wlds[buf] + ct * 1024);
        }
    };

    STAGE_W(0, 0);

    const float* xrow[2];
#pragma unroll
    for (int sub = 0; sub < 2; sub++)
        xrow[sub] = x + (size_t)(mrow0 + wr * 32 + sub * 16 + c) * E_ + g * 8;

    // prologue: x for step 0 into registers
    float4 cx0[2], cx1[2];
#pragma unroll
    for (int sub = 0; sub < 2; sub++) {
        cx0[sub] = *(const float4*)(xrow[sub]);
        cx1[sub] = *(const float4*)(xrow[sub] + 4);
    }

    f32x4 acc[2][6] = {};
    __syncthreads();                 // buf0 staged (implicit vmcnt drain)

    int buf = 0;
    for (int ks = 0; ks < 32; ks++) {
        // issue next-step staging + next-step x loads FIRST (latency hiding)
        float4 nx0[2], nx1[2];
        if (ks < 31) {
            STAGE_W(buf ^ 1, (ks + 1) * 32);
#pragma unroll
            for (int sub = 0; sub < 2; sub++) {
                nx0[sub] = *(const float4*)(xrow[sub] + (ks + 1) * 32);
                nx1[sub] = *(const float4*)(xrow[sub] + (ks + 1) * 32 + 4);
            }
        }

        // convert current x regs -> bf16 A-frags
        bf16x8 av[2];
#pragma unroll
        for (int sub = 0; sub < 2; sub++) {
            union { bf16x8 v; __bf16 e[8]; } a;
            a.e[0] = (__bf16)cx0[sub].x; a.e[1] = (__bf16)cx0[sub].y;
            a.e[2] = (__bf16)cx0[sub].z; a.e[3] = (__bf16)cx0[sub].w;
            a.e[4] = (__bf16)cx1[sub].x; a.e[5] = (__bf16)cx1[sub].y;
            a.e[6] = (__bf16)cx1[sub].z; a.e[7] = (__bf16)cx1[sub].w;
            av[sub] = a.v;
        }

#pragma unroll
        for (int ct = 0; ct < 6; ct++) {
            u16x8 braw = *(const u16x8*)(wlds[buf] + (wc * 6 + ct) * 1024 + l * 16);
            bf16x8 bw = __builtin_bit_cast(bf16x8, braw);
#pragma unroll
            for (int sub = 0; sub < 2; sub++)
                acc[sub][ct] = __builtin_amdgcn_mfma_f32_16x16x32_bf16(av[sub], bw, acc[sub][ct], 0, 0, 0);
        }

        __syncthreads();             // reads done + next staging/x completed
#pragma unroll
        for (int sub = 0; sub < 2; sub++) { cx0[sub] = nx0[sub]; cx1[sub] = nx1[sub]; }
        buf ^= 1;
    }

#pragma unroll
    for (int sub = 0; sub < 2; sub++) {
#pragma unroll
        for (int ct = 0; ct < 6; ct++) {
            int gc = (wc * 6 + ct) * 16;
            int proj = gc >> 7;
            int dcol = gc & 127;
            if (proj < 2) {
                u16* dst = proj ? k : q;
#pragma unroll
                for (int j = 0; j < 4; j++) {
                    int row = mrow0 + wr * 32 + sub * 16 + g * 4 + j;
                    dst[(size_t)row * D_ + dcol + c] = f2bf(acc[sub][ct][j]);
                }
            } else {
                int srow = mrow0 + wr * 32 + sub * 16 + g * 4;
                int b = srow >> 12;
                int s = srow & 4095;
                ushort4 pk;
                pk.x = f2bf(acc[sub][ct][0]);
                pk.y = f2bf(acc[sub][ct][1]);
                pk.z = f2bf(acc[sub][ct][2]);
                pk.w = f2bf(acc[sub][ct][3]);
                *(ushort4*)(vT + ((size_t)(b * D_ + dcol + c)) * S_ + s) = pk;
            }
        }
    }
}

// ---------------------------------------------------------------------------
// Kernel 2: flash attention — UNCHANGED from r14 (best: 97.1us).
// ---------------------------------------------------------------------------
__global__ __launch_bounds__(512) void attn_kernel(const u16* __restrict__ q,
                                                   const u16* __restrict__ k,
                                                   const u16* __restrict__ vT,
                                                   float* __restrict__ out) {
    // bijective XCD-chunk swizzle (nwg=256, 8 XCDs, chunk=32)
    int bid = blockIdx.x;
    int sw = (bid & 7) * 32 + (bid >> 3);
    const int b = sw >> 6;          // batch 0..3 (2 XCDs per batch)
    const int qt = sw & 63;         // q-tile 0..63 (64 rows)
    const int wv = threadIdx.x >> 6;    // 0..7
    const int grp = wv >> 2;            // 0 = even tiles, 1 = odd tiles
    const int wq = wv & 3;              // q-subtile within block
    const int l = threadIdx.x & 63;
    const int g = l >> 4;
    const int c = l & 15;
    const int qrow0 = qt * 64 + wq * 16;   // within batch

    __shared__ __align__(16) char kv_lds[4 * 32768];   // 4 bufs (K 16K | V 16K)
    __shared__ __align__(16) u16 plds[8][1024];        // per-wave 2KB P buffer
    __shared__ float cmB[64], clB[64];
    u16* pw = &plds[wv][0];

    const char* kbb = (const char*)(k + (size_t)b * S_ * D_);
    const char* vbb = (const char*)(vT + (size_t)b * D_ * S_);

    // Q fragments, hoisted (scaled already, via Wq)
    bf16x8 aq[4];
    const u16* qp = q + ((size_t)(b * S_ + qrow0 + c)) * D_ + g * 8;
#pragma unroll
    for (int ks = 0; ks < 4; ks++) aq[ks] = *(const bf16x8*)(qp + ks * 32);

    f32x4 o[8] = {};
    float m[4], ll[4];
#pragma unroll
    for (int j = 0; j < 4; j++) { m[j] = -1e30f; ll[j] = 0.0f; }

    auto STAGE = [&](int buf, int kvbase) {
#pragma unroll
        for (int ii = 0; ii < 4; ii++) {           // K: [64][256B] rows
            int i = wq * 4 + ii;                   // instr 0..15, 1KB each
            int row = i * 4 + (l >> 4);
            int colb = (l & 15) * 16;
            const char* gp = kbb + (size_t)kvbase * 256 + (size_t)row * 256
                           + (colb ^ ((row & 7) << 4));
            gload16(gp, kv_lds + buf * 32768 + i * 1024);
        }
#pragma unroll
        for (int ii = 0; ii < 4; ii++) {           // V: [128][128B] rows
            int i = wq * 4 + ii;
            int row = i * 8 + (l >> 3);
            int colb = (l & 7) * 16;
            const char* gp = vbb + (size_t)row * 8192 + (size_t)kvbase * 2
                           + (colb ^ ((row & 7) << 4));
            gload16(gp, kv_lds + buf * 32768 + 16384 + i * 1024);
        }
    };

    STAGE(grp, grp * 64);
    __syncthreads();                 // drains vmcnt: bufs 0,1 ready
    const int swz = (c & 7) << 4;

    for (int t = 0; t < 32; t++) {
        const int mytile = 2 * t + grp;
        if (t < 31) STAGE((mytile + 2) & 3, (mytile + 2) * 64);

        const char* kbuf = kv_lds + (mytile & 3) * 32768;
        const char* vbuf = kbuf + 16384;

        // ---- S = Q K^T : 4 tiles of 16 kv-cols, K-dim 128 ----
        f32x4 s[4] = {};
        __builtin_amdgcn_s_setprio(1);
#pragma unroll
        for (int tt = 0; tt < 4; tt++) {
            int rb = (tt * 16 + c) * 256;
#pragma unroll
            for (int ks = 0; ks < 4; ks++) {
                u16x8 kr = *(const u16x8*)(kbuf + rb + ((ks * 64 + g * 16) ^ swz));
                bf16x8 bk = __builtin_bit_cast(bf16x8, kr);
                s[tt] = __builtin_amdgcn_mfma_f32_16x16x32_bf16(aq[ks], bk, s[tt], 0, 0, 0);
            }
        }
        __builtin_amdgcn_s_setprio(0);

        // ---- online softmax: DPP reduce + defer-max (THR=8) ----
        float tmj[4];
        bool need = false;
#pragma unroll
        for (int j = 0; j < 4; j++) {
            float tm = fmaxf(fmaxf(s[0][j], s[1][j]), fmaxf(s[2][j], s[3][j]));
            tm = dpp_max16(tm);
            tmj[j] = tm;
            need = need || (tm > m[j] + 8.0f);
        }
        if (__any(need)) {
#pragma unroll
            for (int j = 0; j < 4; j++) {
                float mn = fmaxf(m[j], tmj[j]);
                float alpha = exp2f((m[j] - mn) * 1.44269504f);
                ll[j] *= alpha;
#pragma unroll
                for (int ct = 0; ct < 8; ct++) o[ct][j] *= alpha;
                m[j] = mn;
            }
        }
        float pv[4][4];
#pragma unroll
        for (int j = 0; j < 4; j++) {
            float rs = 0.f;
#pragma unroll
            for (int tt = 0; tt < 4; tt++) {
                float p = exp2f((s[tt][j] - m[j]) * 1.44269504f);
                pv[tt][j] = p;
                rs += p;
            }
            ll[j] += dpp_add16(rs);
        }

        // ---- P -> LDS (wave-private), XOR-swizzled ----
#pragma unroll
        for (int tt = 0; tt < 4; tt++) {
#pragma unroll
            for (int j = 0; j < 4; j++) {
                int r = g * 4 + j;
                int cf = tt * 16 + c;
                int slot = (cf >> 3) ^ ((r & 7) ^ ((r & 8) >> 2));
                pw[r * 64 + slot * 8 + (cf & 7)] = f2bf(pv[tt][j]);
            }
        }

        // ---- PV: O += P[16,64] * V[64,128] ----
        __builtin_amdgcn_s_setprio(1);
#pragma unroll
        for (int st = 0; st < 2; st++) {
            int rho = c;
            int sigma = g + st * 4;
            int slot = sigma ^ ((rho & 7) ^ ((rho & 8) >> 2));
            u16x8 praw = *(const u16x8*)(pw + rho * 64 + slot * 8);
            bf16x8 pa = __builtin_bit_cast(bf16x8, praw);
#pragma unroll
            for (int ct = 0; ct < 8; ct++) {
                int rb = (ct * 16 + c) * 128;
                u16x8 vr = *(const u16x8*)(vbuf + rb + ((st * 64 + g * 16) ^ swz));
                bf16x8 bv = __builtin_bit_cast(bf16x8, vr);
                o[ct] = __builtin_amdgcn_mfma_f32_16x16x32_bf16(pa, bv, o[ct], 0, 0, 0);
            }
        }
        __builtin_amdgcn_s_setprio(0);

        __syncthreads();    // drain staging vmcnt + round barrier
    }

    // ---- 2-way merge: grp 1 -> LDS, grp 0 merges and stores ----
    float* co = (float*)kv_lds;     // 32KB, staging complete
    if (grp == 1) {
#pragma unroll
        for (int ct = 0; ct < 8; ct++) {
#pragma unroll
            for (int j = 0; j < 4; j++)
                co[(size_t)(wq * 16 + g * 4 + j) * 128 + ct * 16 + c] = o[ct][j];
        }
        if (c == 0) {
#pragma unroll
            for (int j = 0; j < 4; j++) {
                cmB[wq * 16 + g * 4 + j] = m[j];
                clB[wq * 16 + g * 4 + j] = ll[j];
            }
        }
    }
    __syncthreads();
    if (grp == 0) {
#pragma unroll
        for (int j = 0; j < 4; j++) {
            int r = wq * 16 + g * 4 + j;
            float mB = cmB[r], lB = clB[r];
            float M = fmaxf(m[j], mB);
            float eA = exp2f((m[j] - M) * 1.44269504f);
            float eB = exp2f((mB - M) * 1.44269504f);
            float rL = 1.0f / (ll[j] * eA + lB * eB);
            float* op = out + ((size_t)(b * S_ + qt * 64 + r)) * D_;
#pragma unroll
            for (int ct = 0; ct < 8; ct++) {
                op[ct * 16 + c] = (o[ct][j] * eA + co[(size_t)r * 128 + ct * 16 + c] * eB) * rL;
            }
        }
    }
}

extern "C" void kernel_launch(void* const* d_in, const int* in_sizes, int n_in,
                              void* d_out, int out_size, void* d_ws, size_t ws_size,
                              hipStream_t stream) {
    const float* x  = (const float*)d_in[0];
    const float* Wq = (const float*)d_in[1];
    const float* Wk = (const float*)d_in[2];
    const float* Wv = (const float*)d_in[3];
    float* out = (float*)d_out;   // reference output dtype is float32

    // workspace layout (bytes): q 4MB | k 4MB | vT 4MB | Wt 768KB
    u16* q  = (u16*)d_ws;
    u16* k  = q  + (size_t)B_ * S_ * D_;
    u16* vT = k  + (size_t)B_ * S_ * D_;
    u16* Wt = vT + (size_t)B_ * S_ * D_;

    wt_kernel<<<(3 * D_ * E_) / 256, 256, 0, stream>>>(Wq, Wk, Wv, Wt);
    qkv_fused<<<(B_ * S_) / 64, 512, 0, stream>>>(x, Wt, q, k, vT);
    attn_kernel<<<(B_ * S_) / 64, 512, 0, stream>>>(q, k, vT, out);
}

// Round 16
// 145.386 us; speedup vs baseline: 1.3810x; 1.1073x over previous
//
#include <hip/hip_runtime.h>
#include <hip/hip_bf16.h>

#define B_ 4
#define S_ 4096
#define E_ 1024
#define D_ 128

typedef unsigned short u16;
typedef __bf16 bf16x8 __attribute__((ext_vector_type(8)));
typedef unsigned short u16x8 __attribute__((ext_vector_type(8)));
typedef float f32x4 __attribute__((ext_vector_type(4)));

__device__ inline u16 f2bf(float f) {
    __bf16 h = (__bf16)f;
    return __builtin_bit_cast(u16, h);
}

// direct global->LDS DMA, 16B per lane, no VGPR round-trip
__device__ inline void gload16(const void* g, void* l) {
    __builtin_amdgcn_global_load_lds(
        (const __attribute__((address_space(1))) void*)g,
        (__attribute__((address_space(3))) void*)l, 16, 0, 0);
}

__device__ inline bf16x8 cvt8(float4 lo, float4 hi) {
    union { bf16x8 v; __bf16 e[8]; } a;
    a.e[0] = (__bf16)lo.x; a.e[1] = (__bf16)lo.y;
    a.e[2] = (__bf16)lo.z; a.e[3] = (__bf16)lo.w;
    a.e[4] = (__bf16)hi.x; a.e[5] = (__bf16)hi.y;
    a.e[6] = (__bf16)hi.z; a.e[7] = (__bf16)hi.w;
    return a.v;
}

// VALU-pipe (DPP) butterfly reductions over 16-lane rows.
__device__ inline float dpp_max16(float x) {
    int v = __builtin_bit_cast(int, x);
    x = fmaxf(x, __builtin_bit_cast(float, __builtin_amdgcn_update_dpp(0, v, 0xB1, 0xF, 0xF, true)));
    v = __builtin_bit_cast(int, x);
    x = fmaxf(x, __builtin_bit_cast(float, __builtin_amdgcn_update_dpp(0, v, 0x4E, 0xF, 0xF, true)));
    v = __builtin_bit_cast(int, x);
    x = fmaxf(x, __builtin_bit_cast(float, __builtin_amdgcn_update_dpp(0, v, 0x141, 0xF, 0xF, true)));
    v = __builtin_bit_cast(int, x);
    x = fmaxf(x, __builtin_bit_cast(float, __builtin_amdgcn_update_dpp(0, v, 0x140, 0xF, 0xF, true)));
    return x;
}
__device__ inline float dpp_add16(float x) {
    int v = __builtin_bit_cast(int, x);
    x += __builtin_bit_cast(float, __builtin_amdgcn_update_dpp(0, v, 0xB1, 0xF, 0xF, true));
    v = __builtin_bit_cast(int, x);
    x += __builtin_bit_cast(float, __builtin_amdgcn_update_dpp(0, v, 0x4E, 0xF, 0xF, true));
    v = __builtin_bit_cast(int, x);
    x += __builtin_bit_cast(float, __builtin_amdgcn_update_dpp(0, v, 0x141, 0xF, 0xF, true));
    v = __builtin_bit_cast(int, x);
    x += __builtin_bit_cast(float, __builtin_amdgcn_update_dpp(0, v, 0x140, 0xF, 0xF, true));
    return x;
}

// ---------------------------------------------------------------------------
// Kernel 0: W [E,D] f32 -> Wt2, the exact per-K-step LDS image:
// Wt2[((w*32+ks)*8 + t8)*64 + l] (16B units) = bf16x8 of
// W_w[e = ks*32 + (l>>4)*8 .. +8][d = t8*16 + (l&15)]  (w=0 pre-scaled).
// Staging then reads 1KB CONTIGUOUS per gload16 (was 16x64B scatter).
// ---------------------------------------------------------------------------
__global__ __launch_bounds__(256) void wt_kernel(const float* __restrict__ Wq,
                                                 const float* __restrict__ Wk,
                                                 const float* __restrict__ Wv,
                                                 u16* __restrict__ Wt) {
    int sid = blockIdx.x * 256 + threadIdx.x;   // 0 .. 49151 (16B slots)
    int l = sid & 63;
    int t8 = (sid >> 6) & 7;
    int ks = (sid >> 9) & 31;
    int w = sid >> 14;
    int g = l >> 4;
    int c = l & 15;
    int d = t8 * 16 + c;
    const float* W = (w == 0) ? Wq : ((w == 1) ? Wk : Wv);
    union { u16x8 v; u16 e[8]; } pk;
#pragma unroll
    for (int jj = 0; jj < 8; jj++) {
        int e = ks * 32 + g * 8 + jj;
        float v = W[(size_t)e * D_ + d];
        if (w == 0) v *= 0.08838834764831845f;   // 1/sqrt(128)
        pk.e[jj] = f2bf(v);
    }
    *(u16x8*)((char*)Wt + (size_t)sid * 16) = pk.v;
}

// ---------------------------------------------------------------------------
// Kernel 1: QKV LDS-staged GEMM, M-tile 64, counted-vmcnt schedule (T3/T4).
// r15 diagnosis: __syncthreads' implicit vmcnt(0) drained the freshly-issued
// x prefetch loads at EVERY step -> each step ate x's ~900cyc HBM latency.
// Now: per step, issue 3 W-stage gload_lds (pinned first via
// sched_barrier(0)), then 4 x-loads for step ks+2 (depth-2 ring, manual
// unroll-2 for static reg indexing); end step with s_waitcnt vmcnt(4) +
// raw s_barrier -> W-stage complete, x loads SPAN the barrier and are
// retired by the compiler's own counted wait at consumption.
// vmcnt(0) only at the tail steps (30) where the x-issue invariant ends.
// ---------------------------------------------------------------------------
__global__ __launch_bounds__(512, 2) void qkv_fused(const float* __restrict__ x,
                                                    const u16* __restrict__ Wt,
                                                    u16* __restrict__ q,
                                                    u16* __restrict__ k,
                                                    u16* __restrict__ vT) {
    const int mrow0 = blockIdx.x * 64;
    const int wv = threadIdx.x >> 6;   // 0..7
    const int l = threadIdx.x & 63;
    const int g = l >> 4;
    const int c = l & 15;
    const int wr = wv >> 2;            // 0..1 (32-row half)
    const int wc = wv & 3;             // 0..3 (96-col group)

    __shared__ __align__(16) char wlds[2][24 * 1024];   // 48 KB dbuf W-tile

    // stage k-step ksIdx: 3 x 1KB CONTIGUOUS reads per wave (Wt2 layout)
    auto STAGE_W = [&](int buf, int ksIdx) {
#pragma unroll
        for (int ii = 0; ii < 3; ii++) {
            int ct = wv * 3 + ii;                  // 0..23 ; w=ct>>3, t8=ct&7
            const char* gp = (const char*)Wt
                + ((size_t)(((ct >> 3) * 32 + ksIdx) * 8 + (ct & 7)) * 1024) + l * 16;
            gload16(gp, wlds[buf] + ct * 1024);
        }
    };

    const float* xrow[2];
#pragma unroll
    for (int sub = 0; sub < 2; sub++)
        xrow[sub] = x + (size_t)(mrow0 + wr * 32 + sub * 16 + c) * E_ + g * 8;

    f32x4 acc[2][6] = {};

    // per-wave MFMA step on buffer `buf` with A-frags av0/av1
    auto MF = [&](int buf, bf16x8 av0, bf16x8 av1) {
#pragma unroll
        for (int ct = 0; ct < 6; ct++) {
            u16x8 braw = *(const u16x8*)(wlds[buf] + (wc * 6 + ct) * 1024 + l * 16);
            bf16x8 bw = __builtin_bit_cast(bf16x8, braw);
            acc[0][ct] = __builtin_amdgcn_mfma_f32_16x16x32_bf16(av0, bw, acc[0][ct], 0, 0, 0);
            acc[1][ct] = __builtin_amdgcn_mfma_f32_16x16x32_bf16(av1, bw, acc[1][ct], 0, 0, 0);
        }
    };

    // prologue: stage step 0; x for steps 0 (slot A) and 1 (slot B)
    STAGE_W(0, 0);
    __builtin_amdgcn_sched_barrier(0);
    float4 xa00 = *(const float4*)(xrow[0]);
    float4 xa01 = *(const float4*)(xrow[0] + 4);
    float4 xa10 = *(const float4*)(xrow[1]);
    float4 xa11 = *(const float4*)(xrow[1] + 4);
    float4 xb00 = *(const float4*)(xrow[0] + 32);
    float4 xb01 = *(const float4*)(xrow[0] + 36);
    float4 xb10 = *(const float4*)(xrow[1] + 32);
    float4 xb11 = *(const float4*)(xrow[1] + 36);
    asm volatile("s_waitcnt vmcnt(8)" ::: "memory");   // stage0 done; x in flight
    __builtin_amdgcn_s_barrier();

    int buf = 0;
    for (int it = 0; it < 16; it++) {
        // ---- even step ks = 2*it : consume slot A ----
        STAGE_W(buf ^ 1, 2 * it + 1);
        __builtin_amdgcn_sched_barrier(0);
        {
            bf16x8 av0 = cvt8(xa00, xa01);
            bf16x8 av1 = cvt8(xa10, xa11);
            if (it < 15) {
                xa00 = *(const float4*)(xrow[0] + (2 * it + 2) * 32);
                xa01 = *(const float4*)(xrow[0] + (2 * it + 2) * 32 + 4);
                xa10 = *(const float4*)(xrow[1] + (2 * it + 2) * 32);
                xa11 = *(const float4*)(xrow[1] + (2 * it + 2) * 32 + 4);
            }
            MF(buf, av0, av1);
        }
        if (it < 15) asm volatile("s_waitcnt vmcnt(4) lgkmcnt(0)" ::: "memory");
        else         asm volatile("s_waitcnt vmcnt(0) lgkmcnt(0)" ::: "memory");
        __builtin_amdgcn_s_barrier();
        buf ^= 1;

        // ---- odd step ks = 2*it+1 : consume slot B ----
        if (it < 15) STAGE_W(buf ^ 1, 2 * it + 2);
        __builtin_amdgcn_sched_barrier(0);
        {
            bf16x8 av0 = cvt8(xb00, xb01);
            bf16x8 av1 = cvt8(xb10, xb11);
            if (it < 15) {
                xb00 = *(const float4*)(xrow[0] + (2 * it + 3) * 32);
                xb01 = *(const float4*)(xrow[0] + (2 * it + 3) * 32 + 4);
                xb10 = *(const float4*)(xrow[1] + (2 * it + 3) * 32);
                xb11 = *(const float4*)(xrow[1] + (2 * it + 3) * 32 + 4);
            }
            MF(buf, av0, av1);
        }
        if (it < 15) {
            asm volatile("s_waitcnt vmcnt(4) lgkmcnt(0)" ::: "memory");
            __builtin_amdgcn_s_barrier();
            buf ^= 1;
        }
    }

    // ---- epilogue (registers only; no barrier needed) ----
#pragma unroll
    for (int sub = 0; sub < 2; sub++) {
#pragma unroll
        for (int ct = 0; ct < 6; ct++) {
            int gc = (wc * 6 + ct) * 16;
            int proj = gc >> 7;
            int dcol = gc & 127;
            if (proj < 2) {
                u16* dst = proj ? k : q;
#pragma unroll
                for (int j = 0; j < 4; j++) {
                    int row = mrow0 + wr * 32 + sub * 16 + g * 4 + j;
                    dst[(size_t)row * D_ + dcol + c] = f2bf(acc[sub][ct][j]);
                }
            } else {
                int srow = mrow0 + wr * 32 + sub * 16 + g * 4;
                int b = srow >> 12;
                int s = srow & 4095;
                ushort4 pk;
                pk.x = f2bf(acc[sub][ct][0]);
                pk.y = f2bf(acc[sub][ct][1]);
                pk.z = f2bf(acc[sub][ct][2]);
                pk.w = f2bf(acc[sub][ct][3]);
                *(ushort4*)(vT + ((size_t)(b * D_ + dcol + c)) * S_ + s) = pk;
            }
        }
    }
}

// ---------------------------------------------------------------------------
// Kernel 2: flash attention — UNCHANGED from r14/r15 (best: 97.1-97.4us).
// ---------------------------------------------------------------------------
__global__ __launch_bounds__(512) void attn_kernel(const u16* __restrict__ q,
                                                   const u16* __restrict__ k,
                                                   const u16* __restrict__ vT,
                                                   float* __restrict__ out) {
    // bijective XCD-chunk swizzle (nwg=256, 8 XCDs, chunk=32)
    int bid = blockIdx.x;
    int sw = (bid & 7) * 32 + (bid >> 3);
    const int b = sw >> 6;          // batch 0..3 (2 XCDs per batch)
    const int qt = sw & 63;         // q-tile 0..63 (64 rows)
    const int wv = threadIdx.x >> 6;    // 0..7
    const int grp = wv >> 2;            // 0 = even tiles, 1 = odd tiles
    const int wq = wv & 3;              // q-subtile within block
    const int l = threadIdx.x & 63;
    const int g = l >> 4;
    const int c = l & 15;
    const int qrow0 = qt * 64 + wq * 16;   // within batch

    __shared__ __align__(16) char kv_lds[4 * 32768];   // 4 bufs (K 16K | V 16K)
    __shared__ __align__(16) u16 plds[8][1024];        // per-wave 2KB P buffer
    __shared__ float cmB[64], clB[64];
    u16* pw = &plds[wv][0];

    const char* kbb = (const char*)(k + (size_t)b * S_ * D_);
    const char* vbb = (const char*)(vT + (size_t)b * D_ * S_);

    // Q fragments, hoisted (scaled already, via Wq)
    bf16x8 aq[4];
    const u16* qp = q + ((size_t)(b * S_ + qrow0 + c)) * D_ + g * 8;
#pragma unroll
    for (int ks = 0; ks < 4; ks++) aq[ks] = *(const bf16x8*)(qp + ks * 32);

    f32x4 o[8] = {};
    float m[4], ll[4];
#pragma unroll
    for (int j = 0; j < 4; j++) { m[j] = -1e30f; ll[j] = 0.0f; }

    auto STAGE = [&](int buf, int kvbase) {
#pragma unroll
        for (int ii = 0; ii < 4; ii++) {           // K: [64][256B] rows
            int i = wq * 4 + ii;                   // instr 0..15, 1KB each
            int row = i * 4 + (l >> 4);
            int colb = (l & 15) * 16;
            const char* gp = kbb + (size_t)kvbase * 256 + (size_t)row * 256
                           + (colb ^ ((row & 7) << 4));
            gload16(gp, kv_lds + buf * 32768 + i * 1024);
        }
#pragma unroll
        for (int ii = 0; ii < 4; ii++) {           // V: [128][128B] rows
            int i = wq * 4 + ii;
            int row = i * 8 + (l >> 3);
            int colb = (l & 7) * 16;
            const char* gp = vbb + (size_t)row * 8192 + (size_t)kvbase * 2
                           + (colb ^ ((row & 7) << 4));
            gload16(gp, kv_lds + buf * 32768 + 16384 + i * 1024);
        }
    };

    STAGE(grp, grp * 64);
    __syncthreads();                 // drains vmcnt: bufs 0,1 ready
    const int swz = (c & 7) << 4;

    for (int t = 0; t < 32; t++) {
        const int mytile = 2 * t + grp;
        if (t < 31) STAGE((mytile + 2) & 3, (mytile + 2) * 64);

        const char* kbuf = kv_lds + (mytile & 3) * 32768;
        const char* vbuf = kbuf + 16384;

        // ---- S = Q K^T : 4 tiles of 16 kv-cols, K-dim 128 ----
        f32x4 s[4] = {};
        __builtin_amdgcn_s_setprio(1);
#pragma unroll
        for (int tt = 0; tt < 4; tt++) {
            int rb = (tt * 16 + c) * 256;
#pragma unroll
            for (int ks = 0; ks < 4; ks++) {
                u16x8 kr = *(const u16x8*)(kbuf + rb + ((ks * 64 + g * 16) ^ swz));
                bf16x8 bk = __builtin_bit_cast(bf16x8, kr);
                s[tt] = __builtin_amdgcn_mfma_f32_16x16x32_bf16(aq[ks], bk, s[tt], 0, 0, 0);
            }
        }
        __builtin_amdgcn_s_setprio(0);

        // ---- online softmax: DPP reduce + defer-max (THR=8) ----
        float tmj[4];
        bool need = false;
#pragma unroll
        for (int j = 0; j < 4; j++) {
            float tm = fmaxf(fmaxf(s[0][j], s[1][j]), fmaxf(s[2][j], s[3][j]));
            tm = dpp_max16(tm);
            tmj[j] = tm;
            need = need || (tm > m[j] + 8.0f);
        }
        if (__any(need)) {
#pragma unroll
            for (int j = 0; j < 4; j++) {
                float mn = fmaxf(m[j], tmj[j]);
                float alpha = exp2f((m[j] - mn) * 1.44269504f);
                ll[j] *= alpha;
#pragma unroll
                for (int ct = 0; ct < 8; ct++) o[ct][j] *= alpha;
                m[j] = mn;
            }
        }
        float pv[4][4];
#pragma unroll
        for (int j = 0; j < 4; j++) {
            float rs = 0.f;
#pragma unroll
            for (int tt = 0; tt < 4; tt++) {
                float p = exp2f((s[tt][j] - m[j]) * 1.44269504f);
                pv[tt][j] = p;
                rs += p;
            }
            ll[j] += dpp_add16(rs);
        }

        // ---- P -> LDS (wave-private), XOR-swizzled ----
#pragma unroll
        for (int tt = 0; tt < 4; tt++) {
#pragma unroll
            for (int j = 0; j < 4; j++) {
                int r = g * 4 + j;
                int cf = tt * 16 + c;
                int slot = (cf >> 3) ^ ((r & 7) ^ ((r & 8) >> 2));
                pw[r * 64 + slot * 8 + (cf & 7)] = f2bf(pv[tt][j]);
            }
        }

        // ---- PV: O += P[16,64] * V[64,128] ----
        __builtin_amdgcn_s_setprio(1);
#pragma unroll
        for (int st = 0; st < 2; st++) {
            int rho = c;
            int sigma = g + st * 4;
            int slot = sigma ^ ((rho & 7) ^ ((rho & 8) >> 2));
            u16x8 praw = *(const u16x8*)(pw + rho * 64 + slot * 8);
            bf16x8 pa = __builtin_bit_cast(bf16x8, praw);
#pragma unroll
            for (int ct = 0; ct < 8; ct++) {
                int rb = (ct * 16 + c) * 128;
                u16x8 vr = *(const u16x8*)(vbuf + rb + ((st * 64 + g * 16) ^ swz));
                bf16x8 bv = __builtin_bit_cast(bf16x8, vr);
                o[ct] = __builtin_amdgcn_mfma_f32_16x16x32_bf16(pa, bv, o[ct], 0, 0, 0);
            }
        }
        __builtin_amdgcn_s_setprio(0);

        __syncthreads();    // drain staging vmcnt + round barrier
    }

    // ---- 2-way merge: grp 1 -> LDS, grp 0 merges and stores ----
    float* co = (float*)kv_lds;     // 32KB, staging complete
    if (grp == 1) {
#pragma unroll
        for (int ct = 0; ct < 8; ct++) {
#pragma unroll
            for (int j = 0; j < 4; j++)
                co[(size_t)(wq * 16 + g * 4 + j) * 128 + ct * 16 + c] = o[ct][j];
        }
        if (c == 0) {
#pragma unroll
            for (int j = 0; j < 4; j++) {
                cmB[wq * 16 + g * 4 + j] = m[j];
                clB[wq * 16 + g * 4 + j] = ll[j];
            }
        }
    }
    __syncthreads();
    if (grp == 0) {
#pragma unroll
        for (int j = 0; j < 4; j++) {
            int r = wq * 16 + g * 4 + j;
            float mB = cmB[r], lB = clB[r];
            float M = fmaxf(m[j], mB);
            float eA = exp2f((m[j] - M) * 1.44269504f);
            float eB = exp2f((mB - M) * 1.44269504f);
            float rL = 1.0f / (ll[j] * eA + lB * eB);
            float* op = out + ((size_t)(b * S_ + qt * 64 + r)) * D_;
#pragma unroll
            for (int ct = 0; ct < 8; ct++) {
                op[ct * 16 + c] = (o[ct][j] * eA + co[(size_t)r * 128 + ct * 16 + c] * eB) * rL;
            }
        }
    }
}

extern "C" void kernel_launch(void* const* d_in, const int* in_sizes, int n_in,
                              void* d_out, int out_size, void* d_ws, size_t ws_size,
                              hipStream_t stream) {
    const float* x  = (const float*)d_in[0];
    const float* Wq = (const float*)d_in[1];
    const float* Wk = (const float*)d_in[2];
    const float* Wv = (const float*)d_in[3];
    float* out = (float*)d_out;   // reference output dtype is float32

    // workspace layout (bytes): q 4MB | k 4MB | vT 4MB | Wt2 768KB
    u16* q  = (u16*)d_ws;
    u16* k  = q  + (size_t)B_ * S_ * D_;
    u16* vT = k  + (size_t)B_ * S_ * D_;
    u16* Wt = vT + (size_t)B_ * S_ * D_;

    wt_kernel<<<(3 * 32 * 8 * 64) / 256, 256, 0, stream>>>(Wq, Wk, Wv, Wt);
    qkv_fused<<<(B_ * S_) / 64, 512, 0, stream>>>(x, Wt, q, k, vT);
    attn_kernel<<<(B_ * S_) / 64, 512, 0, stream>>>(q, k, vT, out);
}